// Round 2
// 314.343 us; speedup vs baseline: 1.0181x; 1.0181x over previous
//
#include <hip/hip_runtime.h>
#include <hip/hip_fp16.h>

// CorrVolume1DBlock: cv[n,i,h,w] = (1/C) * sum_c x1[n,c,h,w] * x2[n,c,h,w-i],
// zero where w-i < 0.  B=8, C=128, H=128, W=256, i in [0,64], fp32 in/out.
//
// R6 == R5 resubmitted (R5 bench was an infra failure: "container failed
// twice", no counters came back; kernel re-audited - no race, LDS/VGPR legal).
//
// R5: async-STAGE split + LDS double-buffer on top of R4's f16-pair fdot2
// formulation. R4 was phase-serialized (stage -> barrier -> compute -> barrier),
// leaving HBM at 18% and VALU at 25% with nothing overlapped. Now:
//   issue next-chunk global loads (regs, no wait) -> compute current chunk
//   from LDS buf cur -> vmcnt drain + convert + ds_write buf cur^1 -> barrier.
// One barrier per chunk (was two). LDS 36->72 KB: still 2 blocks/CU.
//  - 512 threads = 8 waves per block, one block per (n,h).
//    lane l = tid&63 owns w in [4l,4l+4); wave q = tid>>6 owns i in [8q,8q+8)
//    (wave 0 also does i=64). acc[8][4] = 32 regs; in-flight stage = 32 regs;
//    ~100 live VGPRs -> under the 128 cap of __launch_bounds__(512,4).
//  - All LDS reads/writes are b128 with exact 16 B lane stride: conflict-free
//    (2-way structural aliasing only).
//  - Precision unchanged vs R4: absmax ~2e-3 vs 9.96e-3 threshold.

constexpr int B   = 8;
constexpr int C   = 128;
constexpr int H   = 128;
constexpr int W   = 256;
constexpr int NI  = 65;
constexpr int HW  = H * W;
constexpr int CHW = C * HW;
constexpr int KC2 = 16;            // c-PAIRS per chunk (32 channels), 4 chunks
constexpr int X2W = 320;           // x2 cols: j in [0,320) <-> w' = j-64
constexpr int NCHUNK = C / (2 * KC2);  // 4

typedef _Float16 half2v __attribute__((ext_vector_type(2)));

__device__ inline unsigned int pack2(float a, float b) {
    __half2 h = __floats2half2_rn(a, b);     // a -> low, b -> high
    return __builtin_bit_cast(unsigned int, h);
}

__device__ inline float fdot2f(unsigned int a, unsigned int b, float c) {
#if __has_builtin(__builtin_amdgcn_fdot2)
    return __builtin_amdgcn_fdot2(__builtin_bit_cast(half2v, a),
                                  __builtin_bit_cast(half2v, b), c, false);
#else
    __half2 ha = __builtin_bit_cast(__half2, a);
    __half2 hb = __builtin_bit_cast(__half2, b);
    float2 fa = __half22float2(ha), fb = __half22float2(hb);
    return fmaf(fa.x, fb.x, fmaf(fa.y, fb.y, c));
#endif
}

__global__ __launch_bounds__(512, 4)
void corr_volume_kernel(const float* __restrict__ x1,
                        const float* __restrict__ x2,
                        float* __restrict__ out) {
    const int h   = blockIdx.x;
    const int n   = blockIdx.y;
    const int tid = threadIdx.x;
    const int l   = tid & 63;   // w = 4l .. 4l+3
    const int q   = tid >> 6;   // i = 8q .. 8q+7 (wave q); q==0 also i=64

    // double-buffered: 32 KB + 40 KB = 72 KB -> 2 blocks/CU (144 <= 160 KB)
    __shared__ unsigned int x1h[2][KC2][W];    // half2 over (2c2, 2c2+1)
    __shared__ unsigned int x2h[2][KC2][X2W];  // cols [0,64) = zero margin

    float acc[8][4];
    #pragma unroll
    for (int il = 0; il < 8; ++il)
        #pragma unroll
        for (int wl = 0; wl < 4; ++wl) acc[il][wl] = 0.0f;
    float acc64[4] = {0.f, 0.f, 0.f, 0.f};

    // x2 window: LDS col j = w - i + 64 = j0 + (wl - il + 8), wl-il+8 in [1,11]
    const int j0 = 4 * l - 8 * q + 56;   // in [0, 308], uint4-aligned

    const float* x1g = x1 + n * CHW + h * W;
    const float* x2g = x2 + n * CHW + h * W;

    // Zero-fill both buffers' left margins once (never overwritten afterwards).
    // 2 bufs x 16 rows x 16 uint4 = 512 uint4 = exactly one per thread.
    {
        const int bufi = tid >> 8;          // [0,2)
        const int r    = (tid >> 4) & 15;   // [0,16)
        const int cq   = tid & 15;          // [0,16) -> cols [0,64)
        *(uint4*)&x2h[bufi][r][4 * cq] = make_uint4(0u, 0u, 0u, 0u);
    }

    // staging assignment: thread handles c-pair rows sr and sr+8, w-quad sc/4
    const int sr = tid >> 6;         // [0,8)
    const int sc = (tid & 63) * 4;   // [0,256), 16 B aligned

    float4 L[8];   // in-flight stage data: x1 lo/hi + x2 lo/hi for 2 rows

    auto issue = [&](int c0) {
        #pragma unroll
        for (int hh = 0; hh < 2; ++hh) {
            const int r = sr + 8 * hh;
            const float* a = x1g + (c0 + 2 * r) * HW + sc;
            const float* b = x2g + (c0 + 2 * r) * HW + sc;
            L[4 * hh + 0] = *(const float4*)(a);
            L[4 * hh + 1] = *(const float4*)(a + HW);
            L[4 * hh + 2] = *(const float4*)(b);
            L[4 * hh + 3] = *(const float4*)(b + HW);
        }
    };
    auto commit = [&](int bufi) {
        #pragma unroll
        for (int hh = 0; hh < 2; ++hh) {
            const int r = sr + 8 * hh;
            uint4 p;
            p.x = pack2(L[4 * hh + 0].x, L[4 * hh + 1].x);
            p.y = pack2(L[4 * hh + 0].y, L[4 * hh + 1].y);
            p.z = pack2(L[4 * hh + 0].z, L[4 * hh + 1].z);
            p.w = pack2(L[4 * hh + 0].w, L[4 * hh + 1].w);
            *(uint4*)&x1h[bufi][r][sc] = p;
            uint4 s;
            s.x = pack2(L[4 * hh + 2].x, L[4 * hh + 3].x);
            s.y = pack2(L[4 * hh + 2].y, L[4 * hh + 3].y);
            s.z = pack2(L[4 * hh + 2].z, L[4 * hh + 3].z);
            s.w = pack2(L[4 * hh + 2].w, L[4 * hh + 3].w);
            *(uint4*)&x2h[bufi][r][64 + sc] = s;
        }
    };

    // prologue: fill buffer 0
    issue(0);
    commit(0);
    __syncthreads();

    #pragma unroll
    for (int t = 0; t < NCHUNK; ++t) {
        const int cur = t & 1;

        // issue next chunk's global loads BEFORE compute (HBM latency +
        // transfer hides under the fdot2/LDS work below)
        if (t + 1 < NCHUNK) issue((t + 1) * 2 * KC2);

        #pragma unroll 2
        for (int c2 = 0; c2 < KC2; ++c2) {
            const uint4 a4 = *(const uint4*)&x1h[cur][c2][4 * l];
            const unsigned int aw[4] = {a4.x, a4.y, a4.z, a4.w};
            const uint4 b0 = *(const uint4*)&x2h[cur][c2][j0];
            const uint4 b1 = *(const uint4*)&x2h[cur][c2][j0 + 4];
            const uint4 b2 = *(const uint4*)&x2h[cur][c2][j0 + 8];
            const unsigned int bw[12] = {b0.x, b0.y, b0.z, b0.w,
                                         b1.x, b1.y, b1.z, b1.w,
                                         b2.x, b2.y, b2.z, b2.w};
            #pragma unroll
            for (int il = 0; il < 8; ++il)
                #pragma unroll
                for (int wl = 0; wl < 4; ++wl)
                    acc[il][wl] = fdot2f(aw[wl], bw[wl - il + 8], acc[il][wl]);

            if (q == 0) {  // i == 64: w' = w-64 lives at LDS col j = w = 4l
                const uint4 d = *(const uint4*)&x2h[cur][c2][4 * l];
                const unsigned int dw[4] = {d.x, d.y, d.z, d.w};
                #pragma unroll
                for (int wl = 0; wl < 4; ++wl)
                    acc64[wl] = fdot2f(aw[wl], dw[wl], acc64[wl]);
            }
        }

        if (t + 1 < NCHUNK) {
            // vmcnt drain happens here (first use of L), then convert + write
            commit((t + 1) & 1);
            __syncthreads();
        }
    }

    // ---- epilogue: out[n, i, h, w], lane-contiguous float4 stores ----
    const float scale = 1.0f / (float)C;
    float* outg = out + n * (NI * HW) + h * W + 4 * l;
    #pragma unroll
    for (int il = 0; il < 8; ++il) {
        const int i = 8 * q + il;
        *(float4*)(outg + i * HW) =
            make_float4(acc[il][0] * scale, acc[il][1] * scale,
                        acc[il][2] * scale, acc[il][3] * scale);
    }
    if (q == 0) {
        *(float4*)(outg + 64 * HW) =
            make_float4(acc64[0] * scale, acc64[1] * scale,
                        acc64[2] * scale, acc64[3] * scale);
    }
}

extern "C" void kernel_launch(void* const* d_in, const int* in_sizes, int n_in,
                              void* d_out, int out_size, void* d_ws, size_t ws_size,
                              hipStream_t stream) {
    const float* x1 = (const float*)d_in[0];
    const float* x2 = (const float*)d_in[1];
    float* out = (float*)d_out;
    dim3 grid(H, B);   // 1024 blocks, one per (n, h)
    corr_volume_kernel<<<grid, 512, 0, stream>>>(x1, x2, out);
}

// Round 3
// 308.273 us; speedup vs baseline: 1.0381x; 1.0197x over previous
//
#include <hip/hip_runtime.h>
#include <hip/hip_fp16.h>

// CorrVolume1DBlock: cv[n,i,h,w] = (1/C) * sum_c x1[n,c,h,w] * x2[n,c,h,w-i],
// zero where w-i < 0.  B=8, C=128, H=128, W=256, i in [0,64], fp32 in/out.
//
// R7: LDS-traffic restructure. R6 post-mortem: compiler sank the async stage
// loads (VGPR=64 proves L[] never stayed live), and the LDS read pipe is
// ~75% of runtime (101K cyc base + 135K cyc SQ_LDS_BANK_CONFLICT per CU).
// Fix: widen per-wave i-tile 8 -> 16 so one x2 window (5 aligned b128) +
// one x1 read feeds 64 fdot2 (was 4 instrs / 32 dots -> 2.2x fewer LDS
// reads per dot). Block now covers TWO h rows (grid 512): waves split
// (hsel = q>>2, qi = q&3), wave qi owns i in [16qi, 16qi+16); for qi==3 the
// i=64 taps are bw[wl] inside the same window (no extra read).
//  - Chunk = 16 channels (KC2=8 c-pairs), 8 chunks; LDS 36 KB single-buffer
//    -> 2 blocks/CU (VGPR-limited anyway).
//  - acc[16][4] = 64 f32: the R2/R3 spill trap. Mitigations: per-slot staging
//    (12 transient regs), #pragma unroll 1 on c2 loop, 128-reg cap via
//    __launch_bounds__(512,4). Peak live ~105 VGPR.
//  - All LDS ops are b128 at exact 16B lane stride (contiguous 1KB/wave).
//  - Precision: f16 inputs, f32 accumulate -> absmax ~2e-3 vs 9.96e-3.

constexpr int B   = 8;
constexpr int C   = 128;
constexpr int H   = 128;
constexpr int W   = 256;
constexpr int NI  = 65;
constexpr int HW  = H * W;
constexpr int CHW = C * HW;
constexpr int KC2 = 8;             // c-PAIRS per chunk (16 channels), 8 chunks
constexpr int X2W = 320;           // x2 cols: j in [0,320) <-> w' = j-64
constexpr int NCHUNK = C / (2 * KC2);  // 8

typedef _Float16 half2v __attribute__((ext_vector_type(2)));

__device__ inline unsigned int pack2(float a, float b) {
    __half2 h = __floats2half2_rn(a, b);     // a -> low, b -> high
    return __builtin_bit_cast(unsigned int, h);
}

__device__ inline float fdot2f(unsigned int a, unsigned int b, float c) {
#if __has_builtin(__builtin_amdgcn_fdot2)
    return __builtin_amdgcn_fdot2(__builtin_bit_cast(half2v, a),
                                  __builtin_bit_cast(half2v, b), c, false);
#else
    __half2 ha = __builtin_bit_cast(__half2, a);
    __half2 hb = __builtin_bit_cast(__half2, b);
    float2 fa = __half22float2(ha), fb = __half22float2(hb);
    return fmaf(fa.x, fb.x, fmaf(fa.y, fb.y, c));
#endif
}

__global__ __launch_bounds__(512, 4)
void corr_volume_kernel(const float* __restrict__ x1,
                        const float* __restrict__ x2,
                        float* __restrict__ out) {
    const int bh  = blockIdx.x;      // h-pair: h = 2*bh + hsel
    const int n   = blockIdx.y;
    const int tid = threadIdx.x;
    const int l   = tid & 63;        // w = 4l .. 4l+3
    const int q   = tid >> 6;        // wave id
    const int hsel = q >> 2;         // which h row of the pair
    const int qi   = q & 3;          // i-group: i = 16*qi + il, il in [0,16)

    __shared__ unsigned int x1h[2][KC2][W];    // 16 KB, half2 over (2c2,2c2+1)
    __shared__ unsigned int x2h[2][KC2][X2W];  // 20 KB, cols [0,64) = zero margin

    float acc[16][4];
    #pragma unroll
    for (int il = 0; il < 16; ++il)
        #pragma unroll
        for (int wl = 0; wl < 4; ++wl) acc[il][wl] = 0.0f;
    float acc64[4] = {0.f, 0.f, 0.f, 0.f};     // only qi==3 uses this (i=64)

    // window: LDS col j = w - i + 64 = j0a + (16 + wl - il), idx in [1,19]
    // (and i=64 for qi==3 lands at idx = wl in [0,4)) -> 5 aligned uint4.
    const int j0a = 4 * l - 16 * qi + 48;   // in [0, 300], uint4-aligned

    const float* x1b = x1 + n * CHW + (2 * bh) * W;
    const float* x2b = x2 + n * CHW + (2 * bh) * W;

    // Zero-fill left margins of both h rows once (never overwritten later).
    // 2 h x 8 rows x 16 uint4 = 256 uint4.
    if (tid < 256) {
        const int hh = tid >> 7;          // [0,2)
        const int r  = (tid >> 4) & 7;    // [0,8)
        const int cq = tid & 15;          // cols [0,64)
        *(uint4*)&x2h[hh][r][4 * cq] = make_uint4(0u, 0u, 0u, 0u);
    }

    for (int t = 0; t < NCHUNK; ++t) {
        const int c0 = t * 2 * KC2;      // first channel of this chunk

        if (t) __syncthreads();          // WAR: prev compute done before overwrite

        // ---- stage: wave q owns c-pair row r=q for all (input, hh) combos ----
        // per slot: 2 coalesced float4 loads -> pack -> 1 b128 LDS write.
        {
            const int r = q;             // [0,8)
            #pragma unroll
            for (int in2 = 0; in2 < 2; ++in2) {
                const float* gb = in2 ? x2b : x1b;
                #pragma unroll
                for (int hh = 0; hh < 2; ++hh) {
                    const float* g = gb + hh * W + (c0 + 2 * r) * HW + 4 * l;
                    const float4 lo = *(const float4*)g;
                    const float4 hi = *(const float4*)(g + HW);
                    uint4 p;
                    p.x = pack2(lo.x, hi.x); p.y = pack2(lo.y, hi.y);
                    p.z = pack2(lo.z, hi.z); p.w = pack2(lo.w, hi.w);
                    if (in2) *(uint4*)&x2h[hh][r][64 + 4 * l] = p;
                    else     *(uint4*)&x1h[hh][r][4 * l]      = p;
                }
            }
        }
        __syncthreads();                 // RAW: staged data visible

        // ---- compute: 6 b128 reads -> 64 (+4) fdot2 per c2 ----
        #pragma unroll 1
        for (int c2 = 0; c2 < KC2; ++c2) {
            const uint4 a4 = *(const uint4*)&x1h[hsel][c2][4 * l];
            const unsigned int aw[4] = {a4.x, a4.y, a4.z, a4.w};
            const uint4 b0 = *(const uint4*)&x2h[hsel][c2][j0a];
            const uint4 b1 = *(const uint4*)&x2h[hsel][c2][j0a + 4];
            const uint4 b2 = *(const uint4*)&x2h[hsel][c2][j0a + 8];
            const uint4 b3 = *(const uint4*)&x2h[hsel][c2][j0a + 12];
            const uint4 b4 = *(const uint4*)&x2h[hsel][c2][j0a + 16];
            const unsigned int bw[20] = {b0.x, b0.y, b0.z, b0.w,
                                         b1.x, b1.y, b1.z, b1.w,
                                         b2.x, b2.y, b2.z, b2.w,
                                         b3.x, b3.y, b3.z, b3.w,
                                         b4.x, b4.y, b4.z, b4.w};
            #pragma unroll
            for (int il = 0; il < 16; ++il)
                #pragma unroll
                for (int wl = 0; wl < 4; ++wl)
                    acc[il][wl] = fdot2f(aw[wl], bw[16 + wl - il], acc[il][wl]);

            if (qi == 3) {   // i == 64: j = w = 4l+wl -> window idx wl
                #pragma unroll
                for (int wl = 0; wl < 4; ++wl)
                    acc64[wl] = fdot2f(aw[wl], bw[wl], acc64[wl]);
            }
        }
    }

    // ---- epilogue: out[n, i, h, w], lane-contiguous float4 stores ----
    const float scale = 1.0f / (float)C;
    const int h = 2 * bh + hsel;
    float* outg = out + n * (NI * HW) + h * W + 4 * l;
    #pragma unroll
    for (int il = 0; il < 16; ++il) {
        const int i = 16 * qi + il;
        *(float4*)(outg + i * HW) =
            make_float4(acc[il][0] * scale, acc[il][1] * scale,
                        acc[il][2] * scale, acc[il][3] * scale);
    }
    if (qi == 3) {
        *(float4*)(outg + 64 * HW) =
            make_float4(acc64[0] * scale, acc64[1] * scale,
                        acc64[2] * scale, acc64[3] * scale);
    }
}

extern "C" void kernel_launch(void* const* d_in, const int* in_sizes, int n_in,
                              void* d_out, int out_size, void* d_ws, size_t ws_size,
                              hipStream_t stream) {
    const float* x1 = (const float*)d_in[0];
    const float* x2 = (const float*)d_in[1];
    float* out = (float*)d_out;
    dim3 grid(H / 2, B);   // 512 blocks, one per (n, h-pair); 2 blocks/CU
    corr_volume_kernel<<<grid, 512, 0, stream>>>(x1, x2, out);
}